// Round 9
// baseline (249.447 us; speedup 1.0000x reference)
//
#include <hip/hip_runtime.h>
#include <math.h>

#define NN 50000
#define EE 800000
#define DD 128
#define HH 8
#define HDD 16
#define CAP 64     // bucket capacity; P(degree>=64 | Poisson(16)) ~ 1e-18/node
#define GB 391     // ceil(NN/128) gemm tiles
#define TOTB 3519  // GB*9; every 9th block is a GEMM tile, rest are fill
#define PAD 136    // ushorts per LDS row (A tile)

typedef __attribute__((ext_vector_type(8))) short short8;
typedef __attribute__((ext_vector_type(4))) float f32x4;

union U8 { ushort u[8]; int4 v; short8 s; };

__device__ __forceinline__ ushort f2bf(float f) {
    uint u = __float_as_uint(f);
    uint r = (u + 0x7fffu + ((u >> 16) & 1u)) >> 16;
    return (ushort)r;
}
__device__ __forceinline__ float bf2f(ushort u) {
    return __uint_as_float(((uint)u) << 16);
}

// ---------------- prep: pack W^T bf16 (+bias, q scaled) ----------------
__global__ void k_prep(const float* __restrict__ Wq, const float* __restrict__ Wk,
                       const float* __restrict__ Wv, const float* __restrict__ Wo,
                       const float* __restrict__ bq, const float* __restrict__ bk,
                       const float* __restrict__ bv, const float* __restrict__ bo,
                       ushort* __restrict__ Wt, float* __restrict__ bpack) {
    int tid = blockIdx.x * 256 + threadIdx.x;  // 4*128*128
    int w = tid >> 14, rem = tid & 16383, c = rem >> 7, i = rem & 127;
    const float* W = (w == 0) ? Wq : (w == 1) ? Wk : (w == 2) ? Wv : Wo;
    float s = (w == 0) ? 0.25f : 1.0f;
    Wt[(size_t)w * 16384 + c * 128 + i] = f2bf(W[i * 128 + c] * s);
    if (i == 0) {
        const float* B = (w == 0) ? bq : (w == 1) ? bk : (w == 2) ? bv : bo;
        bpack[w * 128 + c] = B[c] * s;
    }
}

// ------- fused pre-pass: QKV MFMA GEMM (blocks %9==0) + bucket fill (rest) --
// GEMM path: lA staged bf16 in LDS (34.8 KB -> 4 blocks/CU); B from global L2.
// Fill path: no barrier, 1 edge/thread.
__global__ __launch_bounds__(256, 4) void k_pre(
    const float* __restrict__ x, const ushort* __restrict__ Wt,
    const float* __restrict__ bpk,
    ushort* __restrict__ qb, ushort* __restrict__ kk, ushort* __restrict__ vv,
    const int* __restrict__ col, const int* __restrict__ row,
    int* __restrict__ cursor, int2* __restrict__ reB) {
    __shared__ ushort lA[128 * PAD];
    int tid = threadIdx.x;
    int b = blockIdx.x;

    if (b % 9 != 0) {
        // ---- bucket fill ----
        int fi = b - b / 9 - 1;               // dense index among fill blocks
        int e = fi * 256 + tid;
        if (e < EE) {
            int c = col[e];
            int p = atomicAdd(&cursor[c], 1);
            if (p < CAP) reB[(size_t)c * CAP + p] = make_int2(row[e], e);
        }
        return;
    }

    // ---- QKV GEMM tile ----
    int tile = b / 9;                         // 0..390
    int lane = tid & 63, wave = tid >> 6;
    int r0 = tile * 128;

    // stage A: fp32 -> bf16, 8 floats per slot
#pragma unroll
    for (int it = 0; it < 8; it++) {
        int slot = it * 256 + tid;            // 0..2047
        int arow = slot >> 4, c8 = slot & 15;
        int ar = min(r0 + arow, NN - 1);
        const float* xp = x + (size_t)ar * 128 + c8 * 8;
        float4 a = *(const float4*)xp;
        float4 bb = *(const float4*)(xp + 4);
        U8 r;
        r.u[0] = f2bf(a.x); r.u[1] = f2bf(a.y); r.u[2] = f2bf(a.z); r.u[3] = f2bf(a.w);
        r.u[4] = f2bf(bb.x); r.u[5] = f2bf(bb.y); r.u[6] = f2bf(bb.z); r.u[7] = f2bf(bb.w);
        *(int4*)&lA[arow * PAD + c8 * 8] = r.v;
    }
    __syncthreads();  // only barrier; lA read-only below

    int wm = wave >> 1, wn = wave & 1;
    int lr = lane & 15, lg = lane >> 4;

    for (int w = 0; w < 3; w++) {
        f32x4 acc[4][4];
#pragma unroll
        for (int m = 0; m < 4; m++)
#pragma unroll
            for (int n = 0; n < 4; n++) acc[m][n] = (f32x4){0.f, 0.f, 0.f, 0.f};

#pragma unroll
        for (int ks = 0; ks < 4; ks++) {
            short8 a[4], bfr[4];
#pragma unroll
            for (int m = 0; m < 4; m++)
                a[m] = *(const short8*)&lA[(wm * 64 + m * 16 + lr) * PAD + ks * 32 + lg * 8];
#pragma unroll
            for (int n = 0; n < 4; n++)
                bfr[n] = *(const short8*)&Wt[(size_t)w * 16384 +
                                             (wn * 64 + n * 16 + lr) * 128 + ks * 32 + lg * 8];
#pragma unroll
            for (int m = 0; m < 4; m++)
#pragma unroll
                for (int n = 0; n < 4; n++)
                    acc[m][n] = __builtin_amdgcn_mfma_f32_16x16x32_bf16(a[m], bfr[n], acc[m][n], 0, 0, 0);
        }

#pragma unroll
        for (int n = 0; n < 4; n++) {
            int gcol = wn * 64 + n * 16 + lr;
            float bv_ = bpk[w * 128 + gcol];
#pragma unroll
            for (int m = 0; m < 4; m++) {
#pragma unroll
                for (int rg = 0; rg < 4; rg++) {
                    int grow = r0 + wm * 64 + m * 16 + lg * 4 + rg;
                    if (grow < NN) {
                        float val = acc[m][n][rg] + bv_;
                        ushort h16 = f2bf(val);
                        if (w == 0)      qb[(size_t)grow * 128 + gcol] = h16;
                        else if (w == 1) kk[(size_t)grow * 128 + gcol] = h16;
                        else             vv[(size_t)grow * 128 + gcol] = h16;
                    }
                }
            }
        }
    }
}

// ---------------- output projection GEMM: LDS-free, B L1-resident ----------
__global__ __launch_bounds__(256) void k_gemm128(
    const ushort* __restrict__ A, const ushort* __restrict__ Bt,
    const float* __restrict__ bias, float* __restrict__ Cf, int M) {
    int tid = threadIdx.x;
    int lane = tid & 63, wave = tid >> 6;
    int r0 = blockIdx.x * 128;
    int wm = wave >> 1, wn = wave & 1;
    int lr = lane & 15, lg = lane >> 4;

    f32x4 acc[4][4];
#pragma unroll
    for (int m = 0; m < 4; m++)
#pragma unroll
        for (int n = 0; n < 4; n++) acc[m][n] = (f32x4){0.f, 0.f, 0.f, 0.f};

#pragma unroll
    for (int ks = 0; ks < 4; ks++) {
        short8 a[4], b[4];
#pragma unroll
        for (int m = 0; m < 4; m++) {
            int ar = min(r0 + wm * 64 + m * 16 + lr, M - 1);
            a[m] = *(const short8*)&A[(size_t)ar * 128 + ks * 32 + lg * 8];
        }
#pragma unroll
        for (int n = 0; n < 4; n++)
            b[n] = *(const short8*)&Bt[(wn * 64 + n * 16 + lr) * 128 + ks * 32 + lg * 8];
#pragma unroll
        for (int m = 0; m < 4; m++)
#pragma unroll
            for (int n = 0; n < 4; n++)
                acc[m][n] = __builtin_amdgcn_mfma_f32_16x16x32_bf16(a[m], b[n], acc[m][n], 0, 0, 0);
    }

#pragma unroll
    for (int n = 0; n < 4; n++) {
        int gcol = wn * 64 + n * 16 + lr;
        float bv_ = bias[gcol];
#pragma unroll
        for (int m = 0; m < 4; m++) {
#pragma unroll
            for (int rg = 0; rg < 4; rg++) {
                int grow = r0 + wm * 64 + m * 16 + lg * 4 + rg;
                if (grow < M) Cf[(size_t)grow * 128 + gcol] = acc[m][n][rg] + bv_;
            }
        }
    }
}

// ---------------- per-node attention, online softmax in registers ----------
// 4 waves/block, 1 node per wave. lane = h*8 + j. q,k,v bf16; bias gathered.
__global__ __launch_bounds__(256) void k_attn(
    const ushort* __restrict__ qb, const ushort* __restrict__ kk,
    const ushort* __restrict__ vv, const float* __restrict__ ebias,
    const int2* __restrict__ reB, const int* __restrict__ deg,
    ushort* __restrict__ aggb) {
    int wave = threadIdx.x >> 6;
    int lane = threadIdx.x & 63;
    int n = blockIdx.x * 4 + wave;
    if (n >= NN) return;
    int cnt = min(deg[n], CAP);
    const int2* bucket = reB + (size_t)n * CAP;
    int h = lane >> 3;
    int j = lane & 7;
    int hb = lane & ~7;

    float qf[16];
    {
        U8 q0, q1;
        const ushort* qp = qb + (size_t)n * DD + h * HDD;
        q0.v = *(const int4*)qp;
        q1.v = *(const int4*)(qp + 8);
#pragma unroll
        for (int t = 0; t < 8; t++) qf[t] = bf2f(q0.u[t]);
#pragma unroll
        for (int t = 0; t < 8; t++) qf[8 + t] = bf2f(q1.u[t]);
    }

    float m = -INFINITY;
    float denom = 0.f;
    float acc0 = 0.f, acc1 = 0.f;

    for (int idx = 0; idx < cnt; idx += 8) {
        int my = idx + j;
        bool valid = my < cnt;
        int2 re = valid ? bucket[my] : make_int2(0, 0);
        int r = re.x;
        float logit = -INFINITY;
        if (valid) {
            const ushort* kp = kk + (size_t)r * DD + h * HDD;
            U8 a0, a1;
            a0.v = *(const int4*)kp;
            a1.v = *(const int4*)(kp + 8);
            float d = 0.f;
#pragma unroll
            for (int t = 0; t < 8; t++) d += qf[t] * bf2f(a0.u[t]);
#pragma unroll
            for (int t = 0; t < 8; t++) d += qf[8 + t] * bf2f(a1.u[t]);
            logit = d + ebias[(size_t)re.y * HH + h];
        }
        float cm = logit;
        cm = fmaxf(cm, __shfl_xor(cm, 1));
        cm = fmaxf(cm, __shfl_xor(cm, 2));
        cm = fmaxf(cm, __shfl_xor(cm, 4));
        float mnew = fmaxf(m, cm);
        float sc = __expf(m - mnew);
        float p = __expf(logit - mnew);
        m = mnew;
        float ps = p;
        ps += __shfl_xor(ps, 1);
        ps += __shfl_xor(ps, 2);
        ps += __shfl_xor(ps, 4);
        denom = denom * sc + ps;
        acc0 *= sc;
        acc1 *= sc;
#pragma unroll
        for (int j2 = 0; j2 < 8; j2++) {
            float pj = __shfl(p, hb + j2);
            int rj = __shfl(r, hb + j2);
            uint vp = *(const uint*)(vv + (size_t)rj * DD + 2 * lane);
            acc0 += pj * bf2f((ushort)(vp & 0xffffu));
            acc1 += pj * bf2f((ushort)(vp >> 16));
        }
    }
    float inv = 1.0f / (denom + 1e-16f);
    uint pack = (uint)f2bf(acc0 * inv) | ((uint)f2bf(acc1 * inv) << 16);
    *(uint*)&aggb[(size_t)n * DD + 2 * lane] = pack;
}

// ---------------- launcher ----------------
extern "C" void kernel_launch(void* const* d_in, const int* in_sizes, int n_in,
                              void* d_out, int out_size, void* d_ws, size_t ws_size,
                              hipStream_t stream) {
    const float* x     = (const float*)d_in[0];
    const int*   eidx  = (const int*)d_in[1];
    const float* ebias = (const float*)d_in[2];
    const float* Wq    = (const float*)d_in[3];
    const float* bq    = (const float*)d_in[4];
    const float* Wk    = (const float*)d_in[5];
    const float* bk    = (const float*)d_in[6];
    const float* Wv    = (const float*)d_in[7];
    const float* bv    = (const float*)d_in[8];
    const float* Wo    = (const float*)d_in[9];
    const float* bo    = (const float*)d_in[10];
    float* out = (float*)d_out;

    const int* row = eidx;        // edge_index[0]
    const int* col = eidx + EE;   // edge_index[1]

    // workspace layout (16B-aligned chunks)
    char* p = (char*)d_ws;
    ushort* qb    = (ushort*)p;  p += (size_t)NN * DD * 2;   // 12.8 MB
    ushort* kk    = (ushort*)p;  p += (size_t)NN * DD * 2;   // 12.8 MB
    ushort* vvp   = (ushort*)p;  p += (size_t)NN * DD * 2;   // 12.8 MB
    ushort* aggb  = (ushort*)p;  p += (size_t)NN * DD * 2;   // 12.8 MB
    ushort* Wt    = (ushort*)p;  p += (size_t)4 * 16384 * 2;
    float*  bpk   = (float*)p;   p += 4 * 128 * 4;
    int2*   reB   = (int2*)p;    p += (size_t)NN * CAP * 8;  // 25.6 MB
    int* cursor   = (int*)p;     p += (size_t)NN * 4;

    hipMemsetAsync(cursor, 0, (size_t)NN * sizeof(int), stream);

    hipLaunchKernelGGL(k_prep, dim3(256), dim3(256), 0, stream,
                       Wq, Wk, Wv, Wo, bq, bk, bv, bo, Wt, bpk);

    hipLaunchKernelGGL(k_pre, dim3(TOTB), dim3(256), 0, stream,
                       x, Wt, bpk, qb, kk, vvp, col, row, cursor, reB);

    hipLaunchKernelGGL(k_attn, dim3(NN / 4), dim3(256), 0, stream,
                       qb, kk, vvp, ebias, reB, cursor, aggb);

    hipLaunchKernelGGL(k_gemm128, dim3(GB), dim3(256), 0, stream,
                       aggb, Wt + 3 * 16384, bpk + 3 * 128, out, NN);
}

// Round 10
// 215.430 us; speedup vs baseline: 1.1579x; 1.1579x over previous
//
#include <hip/hip_runtime.h>
#include <math.h>

#define NN 50000
#define EE 800000
#define DD 128
#define HH 8
#define HDD 16
#define CAP 64     // bucket capacity; P(degree>=64 | Poisson(16)) ~ 1e-18/node
#define GB 391     // ceil(NN/128) gemm tiles
#define TOTB 1954  // GEMM if b%5==0 (391 tiles); else fill (1563 blocks x 512)
#define PAD 136    // ushorts per LDS row (A tile)

typedef __attribute__((ext_vector_type(8))) short short8;
typedef __attribute__((ext_vector_type(4))) float f32x4;

union U8 { ushort u[8]; int4 v; short8 s; };

__device__ __forceinline__ ushort f2bf(float f) {
    uint u = __float_as_uint(f);
    uint r = (u + 0x7fffu + ((u >> 16) & 1u)) >> 16;
    return (ushort)r;
}
__device__ __forceinline__ float bf2f(ushort u) {
    return __uint_as_float(((uint)u) << 16);
}

// ---------------- prep: pack W^T bf16 (+bias, q scaled) ----------------
__global__ void k_prep(const float* __restrict__ Wq, const float* __restrict__ Wk,
                       const float* __restrict__ Wv, const float* __restrict__ Wo,
                       const float* __restrict__ bq, const float* __restrict__ bk,
                       const float* __restrict__ bv, const float* __restrict__ bo,
                       ushort* __restrict__ Wt, float* __restrict__ bpack) {
    int tid = blockIdx.x * 256 + threadIdx.x;  // 4*128*128
    int w = tid >> 14, rem = tid & 16383, c = rem >> 7, i = rem & 127;
    const float* W = (w == 0) ? Wq : (w == 1) ? Wk : (w == 2) ? Wv : Wo;
    float s = (w == 0) ? 0.25f : 1.0f;
    Wt[(size_t)w * 16384 + c * 128 + i] = f2bf(W[i * 128 + c] * s);
    if (i == 0) {
        const float* B = (w == 0) ? bq : (w == 1) ? bk : (w == 2) ? bv : bo;
        bpack[w * 128 + c] = B[c] * s;
    }
}

// ------- fused pre-pass: QKV MFMA GEMM (b%5==0) + bucket fill (rest) --------
// 512 threads. GEMM: 8 waves (2 wm x 4 wn), per-wave 64x32 out -> acc[4][2]
// (32 VGPRs). lA staged bf16 in LDS (34.8 KB); B frags from global Wt.
// launch_bounds(512,4): VGPR<=128, 2 blocks/CU = 16 waves/CU.
__global__ __launch_bounds__(512, 4) void k_pre(
    const float* __restrict__ x, const ushort* __restrict__ Wt,
    const float* __restrict__ bpk,
    ushort* __restrict__ qb, ushort* __restrict__ kk, ushort* __restrict__ vv,
    const int* __restrict__ col, const int* __restrict__ row,
    int* __restrict__ cursor, int2* __restrict__ reB) {
    __shared__ ushort lA[128 * PAD];
    int tid = threadIdx.x;
    int b = blockIdx.x;

    if (b % 5 != 0) {
        // ---- bucket fill ----
        int fi = b - b / 5 - 1;               // dense index among fill blocks
        int e = fi * 512 + tid;
        if (e < EE) {
            int c = col[e];
            int p = atomicAdd(&cursor[c], 1);
            if (p < CAP) reB[(size_t)c * CAP + p] = make_int2(row[e], e);
        }
        return;
    }

    // ---- QKV GEMM tile (128 rows x 128 cols) ----
    int tile = b / 5;                         // 0..390
    int lane = tid & 63, wave = tid >> 6;
    int r0 = tile * 128;

    // stage A: fp32 -> bf16, 8 floats per slot, 4 iters x 512 threads
#pragma unroll
    for (int it = 0; it < 4; it++) {
        int slot = it * 512 + tid;            // 0..2047
        int arow = slot >> 4, c8 = slot & 15;
        int ar = min(r0 + arow, NN - 1);
        const float* xp = x + (size_t)ar * 128 + c8 * 8;
        float4 a = *(const float4*)xp;
        float4 bb = *(const float4*)(xp + 4);
        U8 r;
        r.u[0] = f2bf(a.x); r.u[1] = f2bf(a.y); r.u[2] = f2bf(a.z); r.u[3] = f2bf(a.w);
        r.u[4] = f2bf(bb.x); r.u[5] = f2bf(bb.y); r.u[6] = f2bf(bb.z); r.u[7] = f2bf(bb.w);
        *(int4*)&lA[arow * PAD + c8 * 8] = r.v;
    }
    __syncthreads();  // only barrier; lA read-only below

    int wm = wave >> 2, wn = wave & 3;        // 2 x 4 wave grid
    int lr = lane & 15, lg = lane >> 4;

    for (int w = 0; w < 3; w++) {
        f32x4 acc[4][2];
#pragma unroll
        for (int m = 0; m < 4; m++)
#pragma unroll
            for (int n = 0; n < 2; n++) acc[m][n] = (f32x4){0.f, 0.f, 0.f, 0.f};

#pragma unroll
        for (int ks = 0; ks < 4; ks++) {
            short8 a[4], bfr[2];
#pragma unroll
            for (int m = 0; m < 4; m++)
                a[m] = *(const short8*)&lA[(wm * 64 + m * 16 + lr) * PAD + ks * 32 + lg * 8];
#pragma unroll
            for (int n = 0; n < 2; n++)
                bfr[n] = *(const short8*)&Wt[(size_t)w * 16384 +
                                             (wn * 32 + n * 16 + lr) * 128 + ks * 32 + lg * 8];
#pragma unroll
            for (int m = 0; m < 4; m++)
#pragma unroll
                for (int n = 0; n < 2; n++)
                    acc[m][n] = __builtin_amdgcn_mfma_f32_16x16x32_bf16(a[m], bfr[n], acc[m][n], 0, 0, 0);
        }

#pragma unroll
        for (int n = 0; n < 2; n++) {
            int gcol = wn * 32 + n * 16 + lr;
            float bv_ = bpk[w * 128 + gcol];
#pragma unroll
            for (int m = 0; m < 4; m++) {
#pragma unroll
                for (int rg = 0; rg < 4; rg++) {
                    int grow = r0 + wm * 64 + m * 16 + lg * 4 + rg;
                    if (grow < NN) {
                        float val = acc[m][n][rg] + bv_;
                        ushort h16 = f2bf(val);
                        if (w == 0)      qb[(size_t)grow * 128 + gcol] = h16;
                        else if (w == 1) kk[(size_t)grow * 128 + gcol] = h16;
                        else             vv[(size_t)grow * 128 + gcol] = h16;
                    }
                }
            }
        }
    }
}

// ---------------- output projection GEMM (round-7 LDS version) -------------
__global__ __launch_bounds__(256) void k_gemm128(
    const ushort* __restrict__ A, const ushort* __restrict__ Bt,
    const float* __restrict__ bias, float* __restrict__ Cf, int M) {
    __shared__ ushort lA[128 * PAD];
    __shared__ ushort lB[128 * PAD];
    int tid = threadIdx.x;
    int lane = tid & 63, wave = tid >> 6;
    int r0 = blockIdx.x * 128;

#pragma unroll
    for (int it = 0; it < 8; it++) {
        int slot = it * 256 + tid;
        int row = slot >> 4, c16 = slot & 15;
        int ar = min(r0 + row, M - 1);
        *(int4*)&lA[row * PAD + c16 * 8] = *(const int4*)&A[(size_t)ar * 128 + c16 * 8];
        *(int4*)&lB[row * PAD + c16 * 8] = *(const int4*)&Bt[row * 128 + c16 * 8];
    }
    __syncthreads();

    int wm = wave >> 1, wn = wave & 1;
    int lr = lane & 15, lg = lane >> 4;
    f32x4 acc[4][4];
#pragma unroll
    for (int m = 0; m < 4; m++)
#pragma unroll
        for (int n = 0; n < 4; n++) acc[m][n] = (f32x4){0.f, 0.f, 0.f, 0.f};

#pragma unroll
    for (int ks = 0; ks < 4; ks++) {
        short8 a[4], b[4];
#pragma unroll
        for (int m = 0; m < 4; m++)
            a[m] = *(const short8*)&lA[(wm * 64 + m * 16 + lr) * PAD + ks * 32 + lg * 8];
#pragma unroll
        for (int n = 0; n < 4; n++)
            b[n] = *(const short8*)&lB[(wn * 64 + n * 16 + lr) * PAD + ks * 32 + lg * 8];
#pragma unroll
        for (int m = 0; m < 4; m++)
#pragma unroll
            for (int n = 0; n < 4; n++)
                acc[m][n] = __builtin_amdgcn_mfma_f32_16x16x32_bf16(a[m], b[n], acc[m][n], 0, 0, 0);
    }

#pragma unroll
    for (int n = 0; n < 4; n++) {
        int gcol = wn * 64 + n * 16 + lr;
        float bv_ = bias[gcol];
#pragma unroll
        for (int m = 0; m < 4; m++) {
#pragma unroll
            for (int rg = 0; rg < 4; rg++) {
                int grow = r0 + wm * 64 + m * 16 + lg * 4 + rg;
                if (grow < M) Cf[(size_t)grow * 128 + gcol] = acc[m][n][rg] + bv_;
            }
        }
    }
}

// ---------------- per-node attention, online softmax in registers ----------
// 4 waves/block, 1 node per wave. lane = h*8 + j. q,k,v bf16; bias gathered.
__global__ __launch_bounds__(256) void k_attn(
    const ushort* __restrict__ qb, const ushort* __restrict__ kk,
    const ushort* __restrict__ vv, const float* __restrict__ ebias,
    const int2* __restrict__ reB, const int* __restrict__ deg,
    ushort* __restrict__ aggb) {
    int wave = threadIdx.x >> 6;
    int lane = threadIdx.x & 63;
    int n = blockIdx.x * 4 + wave;
    if (n >= NN) return;
    int cnt = min(deg[n], CAP);
    const int2* bucket = reB + (size_t)n * CAP;
    int h = lane >> 3;
    int j = lane & 7;
    int hb = lane & ~7;

    float qf[16];
    {
        U8 q0, q1;
        const ushort* qp = qb + (size_t)n * DD + h * HDD;
        q0.v = *(const int4*)qp;
        q1.v = *(const int4*)(qp + 8);
#pragma unroll
        for (int t = 0; t < 8; t++) qf[t] = bf2f(q0.u[t]);
#pragma unroll
        for (int t = 0; t < 8; t++) qf[8 + t] = bf2f(q1.u[t]);
    }

    float m = -INFINITY;
    float denom = 0.f;
    float acc0 = 0.f, acc1 = 0.f;

    for (int idx = 0; idx < cnt; idx += 8) {
        int my = idx + j;
        bool valid = my < cnt;
        int2 re = valid ? bucket[my] : make_int2(0, 0);
        int r = re.x;
        float logit = -INFINITY;
        if (valid) {
            const ushort* kp = kk + (size_t)r * DD + h * HDD;
            U8 a0, a1;
            a0.v = *(const int4*)kp;
            a1.v = *(const int4*)(kp + 8);
            float d = 0.f;
#pragma unroll
            for (int t = 0; t < 8; t++) d += qf[t] * bf2f(a0.u[t]);
#pragma unroll
            for (int t = 0; t < 8; t++) d += qf[8 + t] * bf2f(a1.u[t]);
            logit = d + ebias[(size_t)re.y * HH + h];
        }
        float cm = logit;
        cm = fmaxf(cm, __shfl_xor(cm, 1));
        cm = fmaxf(cm, __shfl_xor(cm, 2));
        cm = fmaxf(cm, __shfl_xor(cm, 4));
        float mnew = fmaxf(m, cm);
        float sc = __expf(m - mnew);
        float p = __expf(logit - mnew);
        m = mnew;
        float ps = p;
        ps += __shfl_xor(ps, 1);
        ps += __shfl_xor(ps, 2);
        ps += __shfl_xor(ps, 4);
        denom = denom * sc + ps;
        acc0 *= sc;
        acc1 *= sc;
#pragma unroll
        for (int j2 = 0; j2 < 8; j2++) {
            float pj = __shfl(p, hb + j2);
            int rj = __shfl(r, hb + j2);
            uint vp = *(const uint*)(vv + (size_t)rj * DD + 2 * lane);
            acc0 += pj * bf2f((ushort)(vp & 0xffffu));
            acc1 += pj * bf2f((ushort)(vp >> 16));
        }
    }
    float inv = 1.0f / (denom + 1e-16f);
    uint pack = (uint)f2bf(acc0 * inv) | ((uint)f2bf(acc1 * inv) << 16);
    *(uint*)&aggb[(size_t)n * DD + 2 * lane] = pack;
}

// ---------------- launcher ----------------
extern "C" void kernel_launch(void* const* d_in, const int* in_sizes, int n_in,
                              void* d_out, int out_size, void* d_ws, size_t ws_size,
                              hipStream_t stream) {
    const float* x     = (const float*)d_in[0];
    const int*   eidx  = (const int*)d_in[1];
    const float* ebias = (const float*)d_in[2];
    const float* Wq    = (const float*)d_in[3];
    const float* bq    = (const float*)d_in[4];
    const float* Wk    = (const float*)d_in[5];
    const float* bk    = (const float*)d_in[6];
    const float* Wv    = (const float*)d_in[7];
    const float* bv    = (const float*)d_in[8];
    const float* Wo    = (const float*)d_in[9];
    const float* bo    = (const float*)d_in[10];
    float* out = (float*)d_out;

    const int* row = eidx;        // edge_index[0]
    const int* col = eidx + EE;   // edge_index[1]

    // workspace layout (16B-aligned chunks)
    char* p = (char*)d_ws;
    ushort* qb    = (ushort*)p;  p += (size_t)NN * DD * 2;   // 12.8 MB
    ushort* kk    = (ushort*)p;  p += (size_t)NN * DD * 2;   // 12.8 MB
    ushort* vvp   = (ushort*)p;  p += (size_t)NN * DD * 2;   // 12.8 MB
    ushort* aggb  = (ushort*)p;  p += (size_t)NN * DD * 2;   // 12.8 MB
    ushort* Wt    = (ushort*)p;  p += (size_t)4 * 16384 * 2;
    float*  bpk   = (float*)p;   p += 4 * 128 * 4;
    int2*   reB   = (int2*)p;    p += (size_t)NN * CAP * 8;  // 25.6 MB
    int* cursor   = (int*)p;     p += (size_t)NN * 4;

    hipMemsetAsync(cursor, 0, (size_t)NN * sizeof(int), stream);

    hipLaunchKernelGGL(k_prep, dim3(256), dim3(256), 0, stream,
                       Wq, Wk, Wv, Wo, bq, bk, bv, bo, Wt, bpk);

    hipLaunchKernelGGL(k_pre, dim3(TOTB), dim3(512), 0, stream,
                       x, Wt, bpk, qb, kk, vvp, col, row, cursor, reB);

    hipLaunchKernelGGL(k_attn, dim3(NN / 4), dim3(256), 0, stream,
                       qb, kk, vvp, ebias, reB, cursor, aggb);

    hipLaunchKernelGGL(k_gemm128, dim3(GB), dim3(256), 0, stream,
                       aggb, Wt + 3 * 16384, bpk + 3 * 128, out, NN);
}

// Round 11
// 183.705 us; speedup vs baseline: 1.3579x; 1.1727x over previous
//
#include <hip/hip_runtime.h>
#include <math.h>

#define NN 50000
#define EE 800000
#define DD 128
#define HH 8
#define HDD 16
#define CAP 64      // bucket capacity; P(degree>=64 | Poisson(16)) ~ 1e-18/node
#define NSTRIP 3125 // NN/16 strips of 16 rows
#define QB 782      // ceil(NSTRIP/4) qkv blocks (4 waves = 4 strips each)
#define PREB 3907   // QB qkv blocks (b%5==0) + 3125 fill blocks

typedef __attribute__((ext_vector_type(8))) short short8;
typedef __attribute__((ext_vector_type(4))) float f32x4;

union U8 { ushort u[8]; int4 v; short8 s; };

__device__ __forceinline__ ushort f2bf(float f) {
    uint u = __float_as_uint(f);
    uint r = (u + 0x7fffu + ((u >> 16) & 1u)) >> 16;
    return (ushort)r;
}
__device__ __forceinline__ float bf2f(ushort u) {
    return __uint_as_float(((uint)u) << 16);
}

// ---------------- prep: pack W^T bf16 (+bias, q scaled) ----------------
__global__ void k_prep(const float* __restrict__ Wq, const float* __restrict__ Wk,
                       const float* __restrict__ Wv, const float* __restrict__ Wo,
                       const float* __restrict__ bq, const float* __restrict__ bk,
                       const float* __restrict__ bv, const float* __restrict__ bo,
                       ushort* __restrict__ Wt, float* __restrict__ bpack) {
    int tid = blockIdx.x * 256 + threadIdx.x;  // 4*128*128
    int w = tid >> 14, rem = tid & 16383, c = rem >> 7, i = rem & 127;
    const float* W = (w == 0) ? Wq : (w == 1) ? Wk : (w == 2) ? Wv : Wo;
    float s = (w == 0) ? 0.25f : 1.0f;
    Wt[(size_t)w * 16384 + c * 128 + i] = f2bf(W[i * 128 + c] * s);
    if (i == 0) {
        const float* B = (w == 0) ? bq : (w == 1) ? bk : (w == 2) ? bv : bo;
        bpack[w * 128 + c] = B[c] * s;
    }
}

// ------- fused pre-pass: LDS-free QKV strip-GEMM (b%5==0) + bucket fill -----
// QKV path: each wave computes a 16x128 strip for q,k,v. A-frags from global
// x (fp32->bf16 in regs), B-frags from L1/L2-hot Wt. No LDS, no barrier.
__global__ __launch_bounds__(256) void k_pre(
    const float* __restrict__ x, const ushort* __restrict__ Wt,
    const float* __restrict__ bpk,
    ushort* __restrict__ qb, ushort* __restrict__ kk, ushort* __restrict__ vv,
    const int* __restrict__ col, const int* __restrict__ row,
    int* __restrict__ cursor, int2* __restrict__ reB) {
    int tid = threadIdx.x;
    int b = blockIdx.x;

    if (b % 5 != 0) {
        // ---- bucket fill ----
        int fi = b - b / 5 - 1;               // dense index among fill blocks
        int e = fi * 256 + tid;
        if (e < EE) {
            int c = col[e];
            int p = atomicAdd(&cursor[c], 1);
            if (p < CAP) reB[(size_t)c * CAP + p] = make_int2(row[e], e);
        }
        return;
    }

    // ---- QKV strip (16 rows x 128 cols), one strip per wave ----
    int wave = tid >> 6, lane = tid & 63;
    int strip = (b / 5) * 4 + wave;
    if (strip >= NSTRIP) return;
    int r0 = strip * 16;
    int lr = lane & 15, lg = lane >> 4;

    // A-fragments: row r0+lr, k-slices ks*32 + lg*8 .. +8 (fp32 -> bf16)
    short8 afr[4];
    const float* xp = x + (size_t)(r0 + lr) * 128;
#pragma unroll
    for (int ks = 0; ks < 4; ks++) {
        const float* ap = xp + ks * 32 + lg * 8;
        float4 f0 = *(const float4*)ap;
        float4 f1 = *(const float4*)(ap + 4);
        U8 r;
        r.u[0] = f2bf(f0.x); r.u[1] = f2bf(f0.y); r.u[2] = f2bf(f0.z); r.u[3] = f2bf(f0.w);
        r.u[4] = f2bf(f1.x); r.u[5] = f2bf(f1.y); r.u[6] = f2bf(f1.z); r.u[7] = f2bf(f1.w);
        afr[ks] = r.s;
    }

    for (int w = 0; w < 3; w++) {
        f32x4 acc[8];
#pragma unroll
        for (int n = 0; n < 8; n++) acc[n] = (f32x4){0.f, 0.f, 0.f, 0.f};
        const ushort* Wb = Wt + (size_t)w * 16384;
#pragma unroll
        for (int n = 0; n < 8; n++) {
#pragma unroll
            for (int ks = 0; ks < 4; ks++) {
                short8 bfr = *(const short8*)&Wb[(n * 16 + lr) * 128 + ks * 32 + lg * 8];
                acc[n] = __builtin_amdgcn_mfma_f32_16x16x32_bf16(afr[ks], bfr, acc[n], 0, 0, 0);
            }
        }
        ushort* dst = (w == 0) ? qb : (w == 1) ? kk : vv;
#pragma unroll
        for (int n = 0; n < 8; n++) {
            int gcol = n * 16 + lr;
            float bv_ = bpk[w * 128 + gcol];
#pragma unroll
            for (int rg = 0; rg < 4; rg++) {
                int grow = r0 + lg * 4 + rg;
                dst[(size_t)grow * 128 + gcol] = f2bf(acc[n][rg] + bv_);
            }
        }
    }
}

// ---------------- output projection: LDS-free strip GEMM -------------------
__global__ __launch_bounds__(256) void k_gemm_out(
    const ushort* __restrict__ A, const ushort* __restrict__ Bt,
    const float* __restrict__ bias, float* __restrict__ Cf) {
    int tid = threadIdx.x;
    int wave = tid >> 6, lane = tid & 63;
    int strip = blockIdx.x * 4 + wave;
    if (strip >= NSTRIP) return;
    int r0 = strip * 16;
    int lr = lane & 15, lg = lane >> 4;

    short8 afr[4];
#pragma unroll
    for (int ks = 0; ks < 4; ks++)
        afr[ks] = *(const short8*)&A[(size_t)(r0 + lr) * 128 + ks * 32 + lg * 8];

    f32x4 acc[8];
#pragma unroll
    for (int n = 0; n < 8; n++) acc[n] = (f32x4){0.f, 0.f, 0.f, 0.f};
#pragma unroll
    for (int n = 0; n < 8; n++) {
#pragma unroll
        for (int ks = 0; ks < 4; ks++) {
            short8 bfr = *(const short8*)&Bt[(n * 16 + lr) * 128 + ks * 32 + lg * 8];
            acc[n] = __builtin_amdgcn_mfma_f32_16x16x32_bf16(afr[ks], bfr, acc[n], 0, 0, 0);
        }
    }
#pragma unroll
    for (int n = 0; n < 8; n++) {
        int gcol = n * 16 + lr;
        float bv_ = bias[gcol];
#pragma unroll
        for (int rg = 0; rg < 4; rg++) {
            int grow = r0 + lg * 4 + rg;
            Cf[(size_t)grow * 128 + gcol] = acc[n][rg] + bv_;
        }
    }
}

// ---------------- per-node attention, online softmax in registers ----------
// 4 waves/block, 1 node per wave. lane = h*8 + j. q,k,v bf16; bias gathered.
__global__ __launch_bounds__(256) void k_attn(
    const ushort* __restrict__ qb, const ushort* __restrict__ kk,
    const ushort* __restrict__ vv, const float* __restrict__ ebias,
    const int2* __restrict__ reB, const int* __restrict__ deg,
    ushort* __restrict__ aggb) {
    int wave = threadIdx.x >> 6;
    int lane = threadIdx.x & 63;
    int n = blockIdx.x * 4 + wave;
    if (n >= NN) return;
    int cnt = min(deg[n], CAP);
    const int2* bucket = reB + (size_t)n * CAP;
    int h = lane >> 3;
    int j = lane & 7;
    int hb = lane & ~7;

    float qf[16];
    {
        U8 q0, q1;
        const ushort* qp = qb + (size_t)n * DD + h * HDD;
        q0.v = *(const int4*)qp;
        q1.v = *(const int4*)(qp + 8);
#pragma unroll
        for (int t = 0; t < 8; t++) qf[t] = bf2f(q0.u[t]);
#pragma unroll
        for (int t = 0; t < 8; t++) qf[8 + t] = bf2f(q1.u[t]);
    }

    float m = -INFINITY;
    float denom = 0.f;
    float acc0 = 0.f, acc1 = 0.f;

    for (int idx = 0; idx < cnt; idx += 8) {
        int my = idx + j;
        bool valid = my < cnt;
        int2 re = valid ? bucket[my] : make_int2(0, 0);
        int r = re.x;
        float logit = -INFINITY;
        if (valid) {
            const ushort* kp = kk + (size_t)r * DD + h * HDD;
            U8 a0, a1;
            a0.v = *(const int4*)kp;
            a1.v = *(const int4*)(kp + 8);
            float d = 0.f;
#pragma unroll
            for (int t = 0; t < 8; t++) d += qf[t] * bf2f(a0.u[t]);
#pragma unroll
            for (int t = 0; t < 8; t++) d += qf[8 + t] * bf2f(a1.u[t]);
            logit = d + ebias[(size_t)re.y * HH + h];
        }
        float cm = logit;
        cm = fmaxf(cm, __shfl_xor(cm, 1));
        cm = fmaxf(cm, __shfl_xor(cm, 2));
        cm = fmaxf(cm, __shfl_xor(cm, 4));
        float mnew = fmaxf(m, cm);
        float sc = __expf(m - mnew);
        float p = __expf(logit - mnew);
        m = mnew;
        float ps = p;
        ps += __shfl_xor(ps, 1);
        ps += __shfl_xor(ps, 2);
        ps += __shfl_xor(ps, 4);
        denom = denom * sc + ps;
        acc0 *= sc;
        acc1 *= sc;
#pragma unroll
        for (int j2 = 0; j2 < 8; j2++) {
            float pj = __shfl(p, hb + j2);
            int rj = __shfl(r, hb + j2);
            uint vp = *(const uint*)(vv + (size_t)rj * DD + 2 * lane);
            acc0 += pj * bf2f((ushort)(vp & 0xffffu));
            acc1 += pj * bf2f((ushort)(vp >> 16));
        }
    }
    float inv = 1.0f / (denom + 1e-16f);
    uint pack = (uint)f2bf(acc0 * inv) | ((uint)f2bf(acc1 * inv) << 16);
    *(uint*)&aggb[(size_t)n * DD + 2 * lane] = pack;
}

// ---------------- launcher ----------------
extern "C" void kernel_launch(void* const* d_in, const int* in_sizes, int n_in,
                              void* d_out, int out_size, void* d_ws, size_t ws_size,
                              hipStream_t stream) {
    const float* x     = (const float*)d_in[0];
    const int*   eidx  = (const int*)d_in[1];
    const float* ebias = (const float*)d_in[2];
    const float* Wq    = (const float*)d_in[3];
    const float* bq    = (const float*)d_in[4];
    const float* Wk    = (const float*)d_in[5];
    const float* bk    = (const float*)d_in[6];
    const float* Wv    = (const float*)d_in[7];
    const float* bv    = (const float*)d_in[8];
    const float* Wo    = (const float*)d_in[9];
    const float* bo    = (const float*)d_in[10];
    float* out = (float*)d_out;

    const int* row = eidx;        // edge_index[0]
    const int* col = eidx + EE;   // edge_index[1]

    // workspace layout (16B-aligned chunks)
    char* p = (char*)d_ws;
    ushort* qb    = (ushort*)p;  p += (size_t)NN * DD * 2;   // 12.8 MB
    ushort* kk    = (ushort*)p;  p += (size_t)NN * DD * 2;   // 12.8 MB
    ushort* vvp   = (ushort*)p;  p += (size_t)NN * DD * 2;   // 12.8 MB
    ushort* aggb  = (ushort*)p;  p += (size_t)NN * DD * 2;   // 12.8 MB
    ushort* Wt    = (ushort*)p;  p += (size_t)4 * 16384 * 2;
    float*  bpk   = (float*)p;   p += 4 * 128 * 4;
    int2*   reB   = (int2*)p;    p += (size_t)NN * CAP * 8;  // 25.6 MB
    int* cursor   = (int*)p;     p += (size_t)NN * 4;

    hipMemsetAsync(cursor, 0, (size_t)NN * sizeof(int), stream);

    hipLaunchKernelGGL(k_prep, dim3(256), dim3(256), 0, stream,
                       Wq, Wk, Wv, Wo, bq, bk, bv, bo, Wt, bpk);

    hipLaunchKernelGGL(k_pre, dim3(PREB), dim3(256), 0, stream,
                       x, Wt, bpk, qb, kk, vvp, col, row, cursor, reB);

    hipLaunchKernelGGL(k_attn, dim3(NN / 4), dim3(256), 0, stream,
                       qb, kk, vvp, ebias, reB, cursor, aggb);

    hipLaunchKernelGGL(k_gemm_out, dim3(QB), dim3(256), 0, stream,
                       aggb, Wt + 3 * 16384, bpk + 3 * 128, out);
}

// Round 12
// 181.770 us; speedup vs baseline: 1.3723x; 1.0106x over previous
//
#include <hip/hip_runtime.h>
#include <math.h>

#define NN 50000
#define EE 800000
#define DD 128
#define HH 8
#define HDD 16
#define CAP 64      // bucket capacity; P(degree>=64 | Poisson(16)) ~ 1e-18/node
#define NSTRIP 3125 // NN/16 strips of 16 rows
#define QB 782      // ceil(NSTRIP/4) qkv blocks (4 waves = 4 strips each)
#define PREB 3907   // 782 qkv blocks (b%5==0) + 3125 fill blocks
#define LTS 130     // padded ushort stride for transpose buffer

typedef __attribute__((ext_vector_type(8))) short short8;
typedef __attribute__((ext_vector_type(4))) float f32x4;

union U8 { ushort u[8]; int4 v; short8 s; };

__device__ __forceinline__ ushort f2bf(float f) {
    uint u = __float_as_uint(f);
    uint r = (u + 0x7fffu + ((u >> 16) & 1u)) >> 16;
    return (ushort)r;
}
__device__ __forceinline__ float bf2f(ushort u) {
    return __uint_as_float(((uint)u) << 16);
}

// ---------------- prep: pack W^T bf16 (+bias, q scaled) ----------------
__global__ void k_prep(const float* __restrict__ Wq, const float* __restrict__ Wk,
                       const float* __restrict__ Wv, const float* __restrict__ Wo,
                       const float* __restrict__ bq, const float* __restrict__ bk,
                       const float* __restrict__ bv, const float* __restrict__ bo,
                       ushort* __restrict__ Wt, float* __restrict__ bpack) {
    int tid = blockIdx.x * 256 + threadIdx.x;  // 4*128*128
    int w = tid >> 14, rem = tid & 16383, c = rem >> 7, i = rem & 127;
    const float* W = (w == 0) ? Wq : (w == 1) ? Wk : (w == 2) ? Wv : Wo;
    float s = (w == 0) ? 0.25f : 1.0f;
    Wt[(size_t)w * 16384 + c * 128 + i] = f2bf(W[i * 128 + c] * s);
    if (i == 0) {
        const float* B = (w == 0) ? bq : (w == 1) ? bk : (w == 2) ? bv : bo;
        bpack[w * 128 + c] = B[c] * s;
    }
}

// ------- fused pre-pass: LDS-free QKV strip-GEMM (b%5==0) + bucket fill -----
// QKV: per wave one 16x128 strip. ks-outer/n-inner: 8 independent B-loads then
// 8 independent MFMAs per ks round (ILP). Epilogue: per-wave LDS transpose ->
// 4x coalesced 1KB stores.
__global__ __launch_bounds__(256) void k_pre(
    const float* __restrict__ x, const ushort* __restrict__ Wt,
    const float* __restrict__ bpk,
    ushort* __restrict__ qb, ushort* __restrict__ kk, ushort* __restrict__ vv,
    const int* __restrict__ col, const int* __restrict__ row,
    int* __restrict__ cursor, int2* __restrict__ reB) {
    __shared__ ushort T[4][16 * LTS];  // 16.6 KB
    int tid = threadIdx.x;
    int b = blockIdx.x;

    if (b % 5 != 0) {
        // ---- bucket fill ----
        int fi = b - b / 5 - 1;               // dense index among fill blocks
        int e = fi * 256 + tid;
        if (e < EE) {
            int c = col[e];
            int p = atomicAdd(&cursor[c], 1);
            if (p < CAP) reB[(size_t)c * CAP + p] = make_int2(row[e], e);
        }
        return;
    }

    // ---- QKV strip (16 rows x 128 cols), one strip per wave ----
    int wave = tid >> 6, lane = tid & 63;
    int strip = (b / 5) * 4 + wave;
    if (strip >= NSTRIP) return;
    int r0 = strip * 16;
    int lr = lane & 15, lg = lane >> 4;
    ushort* Tw = T[wave];

    // A-fragments: row r0+lr, k-slices ks*32 + lg*8 (fp32 -> bf16)
    short8 afr[4];
    const float* xp = x + (size_t)(r0 + lr) * 128;
#pragma unroll
    for (int ks = 0; ks < 4; ks++) {
        const float* ap = xp + ks * 32 + lg * 8;
        float4 f0 = *(const float4*)ap;
        float4 f1 = *(const float4*)(ap + 4);
        U8 r;
        r.u[0] = f2bf(f0.x); r.u[1] = f2bf(f0.y); r.u[2] = f2bf(f0.z); r.u[3] = f2bf(f0.w);
        r.u[4] = f2bf(f1.x); r.u[5] = f2bf(f1.y); r.u[6] = f2bf(f1.z); r.u[7] = f2bf(f1.w);
        afr[ks] = r.s;
    }

    for (int w = 0; w < 3; w++) {
        f32x4 acc[8];
#pragma unroll
        for (int n = 0; n < 8; n++) acc[n] = (f32x4){0.f, 0.f, 0.f, 0.f};
        const ushort* Wb = Wt + (size_t)w * 16384;
#pragma unroll
        for (int ks = 0; ks < 4; ks++) {
            short8 bfr[8];
#pragma unroll
            for (int n = 0; n < 8; n++)
                bfr[n] = *(const short8*)&Wb[(n * 16 + lr) * 128 + ks * 32 + lg * 8];
#pragma unroll
            for (int n = 0; n < 8; n++)
                acc[n] = __builtin_amdgcn_mfma_f32_16x16x32_bf16(afr[ks], bfr[n], acc[n], 0, 0, 0);
        }

        // epilogue: transpose via per-wave LDS, then coalesced 1KB stores
#pragma unroll
        for (int n = 0; n < 8; n++) {
            float bv_ = bpk[w * 128 + n * 16 + lr];
#pragma unroll
            for (int rg = 0; rg < 4; rg++)
                Tw[(lg * 4 + rg) * LTS + n * 16 + lr] = f2bf(acc[n][rg] + bv_);
        }
        ushort* dst = (w == 0) ? qb : (w == 1) ? kk : vv;
#pragma unroll
        for (int i = 0; i < 4; i++) {
            // lane covers global bytes r0*256 + i*1024 + lane*16 (fully coalesced)
            int4 vd = *(const int4*)&Tw[(i * 4 + lg) * LTS + lr * 8];
            *(int4*)&dst[(size_t)(r0 + i * 4 + lg) * 128 + lr * 8] = vd;
        }
    }
}

// ---------------- output projection: LDS-free strip GEMM (ks-outer ILP) ----
__global__ __launch_bounds__(256) void k_gemm_out(
    const ushort* __restrict__ A, const ushort* __restrict__ Bt,
    const float* __restrict__ bias, float* __restrict__ Cf) {
    int tid = threadIdx.x;
    int wave = tid >> 6, lane = tid & 63;
    int strip = blockIdx.x * 4 + wave;
    if (strip >= NSTRIP) return;
    int r0 = strip * 16;
    int lr = lane & 15, lg = lane >> 4;

    short8 afr[4];
#pragma unroll
    for (int ks = 0; ks < 4; ks++)
        afr[ks] = *(const short8*)&A[(size_t)(r0 + lr) * 128 + ks * 32 + lg * 8];

    f32x4 acc[8];
#pragma unroll
    for (int n = 0; n < 8; n++) acc[n] = (f32x4){0.f, 0.f, 0.f, 0.f};
#pragma unroll
    for (int ks = 0; ks < 4; ks++) {
        short8 bfr[8];
#pragma unroll
        for (int n = 0; n < 8; n++)
            bfr[n] = *(const short8*)&Bt[(n * 16 + lr) * 128 + ks * 32 + lg * 8];
#pragma unroll
        for (int n = 0; n < 8; n++)
            acc[n] = __builtin_amdgcn_mfma_f32_16x16x32_bf16(afr[ks], bfr[n], acc[n], 0, 0, 0);
    }
#pragma unroll
    for (int n = 0; n < 8; n++) {
        int gcol = n * 16 + lr;
        float bv_ = bias[gcol];
#pragma unroll
        for (int rg = 0; rg < 4; rg++) {
            int grow = r0 + lg * 4 + rg;
            Cf[(size_t)grow * 128 + gcol] = acc[n][rg] + bv_;  // full 64B lines
        }
    }
}

// ---------------- per-node attention, online softmax in registers ----------
// 4 waves/block, 1 node per wave. lane = h*8 + j. q,k,v bf16; bias gathered.
__global__ __launch_bounds__(256) void k_attn(
    const ushort* __restrict__ qb, const ushort* __restrict__ kk,
    const ushort* __restrict__ vv, const float* __restrict__ ebias,
    const int2* __restrict__ reB, const int* __restrict__ deg,
    ushort* __restrict__ aggb) {
    int wave = threadIdx.x >> 6;
    int lane = threadIdx.x & 63;
    int n = blockIdx.x * 4 + wave;
    if (n >= NN) return;
    int cnt = min(deg[n], CAP);
    const int2* bucket = reB + (size_t)n * CAP;
    int h = lane >> 3;
    int j = lane & 7;
    int hb = lane & ~7;

    float qf[16];
    {
        U8 q0, q1;
        const ushort* qp = qb + (size_t)n * DD + h * HDD;
        q0.v = *(const int4*)qp;
        q1.v = *(const int4*)(qp + 8);
#pragma unroll
        for (int t = 0; t < 8; t++) qf[t] = bf2f(q0.u[t]);
#pragma unroll
        for (int t = 0; t < 8; t++) qf[8 + t] = bf2f(q1.u[t]);
    }

    float m = -INFINITY;
    float denom = 0.f;
    float acc0 = 0.f, acc1 = 0.f;

    for (int idx = 0; idx < cnt; idx += 8) {
        int my = idx + j;
        bool valid = my < cnt;
        int2 re = valid ? bucket[my] : make_int2(0, 0);
        int r = re.x;
        float logit = -INFINITY;
        if (valid) {
            const ushort* kp = kk + (size_t)r * DD + h * HDD;
            U8 a0, a1;
            a0.v = *(const int4*)kp;
            a1.v = *(const int4*)(kp + 8);
            float d = 0.f;
#pragma unroll
            for (int t = 0; t < 8; t++) d += qf[t] * bf2f(a0.u[t]);
#pragma unroll
            for (int t = 0; t < 8; t++) d += qf[8 + t] * bf2f(a1.u[t]);
            logit = d + ebias[(size_t)re.y * HH + h];
        }
        float cm = logit;
        cm = fmaxf(cm, __shfl_xor(cm, 1));
        cm = fmaxf(cm, __shfl_xor(cm, 2));
        cm = fmaxf(cm, __shfl_xor(cm, 4));
        float mnew = fmaxf(m, cm);
        float sc = __expf(m - mnew);
        float p = __expf(logit - mnew);
        m = mnew;
        float ps = p;
        ps += __shfl_xor(ps, 1);
        ps += __shfl_xor(ps, 2);
        ps += __shfl_xor(ps, 4);
        denom = denom * sc + ps;
        acc0 *= sc;
        acc1 *= sc;
#pragma unroll
        for (int j2 = 0; j2 < 8; j2++) {
            float pj = __shfl(p, hb + j2);
            int rj = __shfl(r, hb + j2);
            uint vp = *(const uint*)(vv + (size_t)rj * DD + 2 * lane);
            acc0 += pj * bf2f((ushort)(vp & 0xffffu));
            acc1 += pj * bf2f((ushort)(vp >> 16));
        }
    }
    float inv = 1.0f / (denom + 1e-16f);
    uint pack = (uint)f2bf(acc0 * inv) | ((uint)f2bf(acc1 * inv) << 16);
    *(uint*)&aggb[(size_t)n * DD + 2 * lane] = pack;
}

// ---------------- launcher ----------------
extern "C" void kernel_launch(void* const* d_in, const int* in_sizes, int n_in,
                              void* d_out, int out_size, void* d_ws, size_t ws_size,
                              hipStream_t stream) {
    const float* x     = (const float*)d_in[0];
    const int*   eidx  = (const int*)d_in[1];
    const float* ebias = (const float*)d_in[2];
    const float* Wq    = (const float*)d_in[3];
    const float* bq    = (const float*)d_in[4];
    const float* Wk    = (const float*)d_in[5];
    const float* bk    = (const float*)d_in[6];
    const float* Wv    = (const float*)d_in[7];
    const float* bv    = (const float*)d_in[8];
    const float* Wo    = (const float*)d_in[9];
    const float* bo    = (const float*)d_in[10];
    float* out = (float*)d_out;

    const int* row = eidx;        // edge_index[0]
    const int* col = eidx + EE;   // edge_index[1]

    // workspace layout (16B-aligned chunks)
    char* p = (char*)d_ws;
    ushort* qb    = (ushort*)p;  p += (size_t)NN * DD * 2;   // 12.8 MB
    ushort* kk    = (ushort*)p;  p += (size_t)NN * DD * 2;   // 12.8 MB
    ushort* vvp   = (ushort*)p;  p += (size_t)NN * DD * 2;   // 12.8 MB
    ushort* aggb  = (ushort*)p;  p += (size_t)NN * DD * 2;   // 12.8 MB
    ushort* Wt    = (ushort*)p;  p += (size_t)4 * 16384 * 2;
    float*  bpk   = (float*)p;   p += 4 * 128 * 4;
    int2*   reB   = (int2*)p;    p += (size_t)NN * CAP * 8;  // 25.6 MB
    int* cursor   = (int*)p;     p += (size_t)NN * 4;

    hipMemsetAsync(cursor, 0, (size_t)NN * sizeof(int), stream);

    hipLaunchKernelGGL(k_prep, dim3(256), dim3(256), 0, stream,
                       Wq, Wk, Wv, Wo, bq, bk, bv, bo, Wt, bpk);

    hipLaunchKernelGGL(k_pre, dim3(PREB), dim3(256), 0, stream,
                       x, Wt, bpk, qb, kk, vvp, col, row, cursor, reB);

    hipLaunchKernelGGL(k_attn, dim3(NN / 4), dim3(256), 0, stream,
                       qb, kk, vvp, ebias, reB, cursor, aggb);

    hipLaunchKernelGGL(k_gemm_out, dim3(QB), dim3(256), 0, stream,
                       aggb, Wt + 3 * 16384, bpk + 3 * 128, out);
}

// Round 13
// 180.658 us; speedup vs baseline: 1.3808x; 1.0062x over previous
//
#include <hip/hip_runtime.h>
#include <math.h>

#define NN 50000
#define EE 800000
#define DD 128
#define HH 8
#define HDD 16
#define CAP 64      // bucket capacity; P(degree>=64 | Poisson(16)) ~ 1e-18/node
#define CSTR 16     // cursor stride (ints): one counter per 64B line
#define NSTRIP 3125 // NN/16 strips of 16 rows
#define QB 782      // ceil(NSTRIP/4) qkv blocks (4 waves = 4 strips each)
#define PREB 3907   // 782 qkv blocks (b%5==0) + 3125 fill blocks
#define LTS 130     // padded ushort stride for transpose buffer

typedef __attribute__((ext_vector_type(8))) short short8;
typedef __attribute__((ext_vector_type(4))) float f32x4;

union U8 { ushort u[8]; int4 v; short8 s; };

__device__ __forceinline__ ushort f2bf(float f) {
    uint u = __float_as_uint(f);
    uint r = (u + 0x7fffu + ((u >> 16) & 1u)) >> 16;
    return (ushort)r;
}
__device__ __forceinline__ float bf2f(ushort u) {
    return __uint_as_float(((uint)u) << 16);
}

// ---------------- prep: pack W^T bf16 (+bias, q scaled) ----------------
__global__ void k_prep(const float* __restrict__ Wq, const float* __restrict__ Wk,
                       const float* __restrict__ Wv, const float* __restrict__ Wo,
                       const float* __restrict__ bq, const float* __restrict__ bk,
                       const float* __restrict__ bv, const float* __restrict__ bo,
                       ushort* __restrict__ Wt, float* __restrict__ bpack) {
    int tid = blockIdx.x * 256 + threadIdx.x;  // 4*128*128
    int w = tid >> 14, rem = tid & 16383, c = rem >> 7, i = rem & 127;
    const float* W = (w == 0) ? Wq : (w == 1) ? Wk : (w == 2) ? Wv : Wo;
    float s = (w == 0) ? 0.25f : 1.0f;
    Wt[(size_t)w * 16384 + c * 128 + i] = f2bf(W[i * 128 + c] * s);
    if (i == 0) {
        const float* B = (w == 0) ? bq : (w == 1) ? bk : (w == 2) ? bv : bo;
        bpack[w * 128 + c] = B[c] * s;
    }
}

// ------- fused pre-pass: LDS-free QKV strip-GEMM (b%5==0) + bucket fill -----
// Fill: cursor padded to 1 counter / 64B line (kills same-line atomic serial).
__global__ __launch_bounds__(256) void k_pre(
    const float* __restrict__ x, const ushort* __restrict__ Wt,
    const float* __restrict__ bpk,
    ushort* __restrict__ qb, ushort* __restrict__ kk, ushort* __restrict__ vv,
    const int* __restrict__ col, const int* __restrict__ row,
    int* __restrict__ cursor, int2* __restrict__ reB) {
    __shared__ ushort T[4][16 * LTS];  // 16.6 KB
    int tid = threadIdx.x;
    int b = blockIdx.x;

    if (b % 5 != 0) {
        // ---- bucket fill ----
        int fi = b - b / 5 - 1;               // dense index among fill blocks
        int e = fi * 256 + tid;
        if (e < EE) {
            int c = col[e];
            int p = atomicAdd(&cursor[(size_t)c * CSTR], 1);
            if (p < CAP) reB[(size_t)c * CAP + p] = make_int2(row[e], e);
        }
        return;
    }

    // ---- QKV strip (16 rows x 128 cols), one strip per wave ----
    int wave = tid >> 6, lane = tid & 63;
    int strip = (b / 5) * 4 + wave;
    if (strip >= NSTRIP) return;
    int r0 = strip * 16;
    int lr = lane & 15, lg = lane >> 4;
    ushort* Tw = T[wave];

    // A-fragments: row r0+lr, k-slices ks*32 + lg*8 (fp32 -> bf16)
    short8 afr[4];
    const float* xp = x + (size_t)(r0 + lr) * 128;
#pragma unroll
    for (int ks = 0; ks < 4; ks++) {
        const float* ap = xp + ks * 32 + lg * 8;
        float4 f0 = *(const float4*)ap;
        float4 f1 = *(const float4*)(ap + 4);
        U8 r;
        r.u[0] = f2bf(f0.x); r.u[1] = f2bf(f0.y); r.u[2] = f2bf(f0.z); r.u[3] = f2bf(f0.w);
        r.u[4] = f2bf(f1.x); r.u[5] = f2bf(f1.y); r.u[6] = f2bf(f1.z); r.u[7] = f2bf(f1.w);
        afr[ks] = r.s;
    }

    for (int w = 0; w < 3; w++) {
        f32x4 acc[8];
#pragma unroll
        for (int n = 0; n < 8; n++) acc[n] = (f32x4){0.f, 0.f, 0.f, 0.f};
        const ushort* Wb = Wt + (size_t)w * 16384;
#pragma unroll
        for (int ks = 0; ks < 4; ks++) {
            short8 bfr[8];
#pragma unroll
            for (int n = 0; n < 8; n++)
                bfr[n] = *(const short8*)&Wb[(n * 16 + lr) * 128 + ks * 32 + lg * 8];
#pragma unroll
            for (int n = 0; n < 8; n++)
                acc[n] = __builtin_amdgcn_mfma_f32_16x16x32_bf16(afr[ks], bfr[n], acc[n], 0, 0, 0);
        }

        // epilogue: transpose via per-wave LDS, then coalesced 1KB stores
#pragma unroll
        for (int n = 0; n < 8; n++) {
            float bv_ = bpk[w * 128 + n * 16 + lr];
#pragma unroll
            for (int rg = 0; rg < 4; rg++)
                Tw[(lg * 4 + rg) * LTS + n * 16 + lr] = f2bf(acc[n][rg] + bv_);
        }
        ushort* dst = (w == 0) ? qb : (w == 1) ? kk : vv;
#pragma unroll
        for (int i = 0; i < 4; i++) {
            int4 vd = *(const int4*)&Tw[(i * 4 + lg) * LTS + lr * 8];
            *(int4*)&dst[(size_t)(r0 + i * 4 + lg) * 128 + lr * 8] = vd;
        }
    }
}

// ---------------- output projection: LDS-free strip GEMM -------------------
__global__ __launch_bounds__(256) void k_gemm_out(
    const ushort* __restrict__ A, const ushort* __restrict__ Bt,
    const float* __restrict__ bias, float* __restrict__ Cf) {
    int tid = threadIdx.x;
    int wave = tid >> 6, lane = tid & 63;
    int strip = blockIdx.x * 4 + wave;
    if (strip >= NSTRIP) return;
    int r0 = strip * 16;
    int lr = lane & 15, lg = lane >> 4;

    short8 afr[4];
#pragma unroll
    for (int ks = 0; ks < 4; ks++)
        afr[ks] = *(const short8*)&A[(size_t)(r0 + lr) * 128 + ks * 32 + lg * 8];

    f32x4 acc[8];
#pragma unroll
    for (int n = 0; n < 8; n++) acc[n] = (f32x4){0.f, 0.f, 0.f, 0.f};
#pragma unroll
    for (int ks = 0; ks < 4; ks++) {
        short8 bfr[8];
#pragma unroll
        for (int n = 0; n < 8; n++)
            bfr[n] = *(const short8*)&Bt[(n * 16 + lr) * 128 + ks * 32 + lg * 8];
#pragma unroll
        for (int n = 0; n < 8; n++)
            acc[n] = __builtin_amdgcn_mfma_f32_16x16x32_bf16(afr[ks], bfr[n], acc[n], 0, 0, 0);
    }
#pragma unroll
    for (int n = 0; n < 8; n++) {
        int gcol = n * 16 + lr;
        float bv_ = bias[gcol];
#pragma unroll
        for (int rg = 0; rg < 4; rg++) {
            int grow = r0 + lg * 4 + rg;
            Cf[(size_t)grow * 128 + gcol] = acc[n][rg] + bv_;
        }
    }
}

// ---------------- per-node attention, online softmax in registers ----------
__global__ __launch_bounds__(256) void k_attn(
    const ushort* __restrict__ qb, const ushort* __restrict__ kk,
    const ushort* __restrict__ vv, const float* __restrict__ ebias,
    const int2* __restrict__ reB, const int* __restrict__ deg,
    ushort* __restrict__ aggb) {
    int wave = threadIdx.x >> 6;
    int lane = threadIdx.x & 63;
    int n = blockIdx.x * 4 + wave;
    if (n >= NN) return;
    int cnt = min(deg[(size_t)n * CSTR], CAP);
    const int2* bucket = reB + (size_t)n * CAP;
    int h = lane >> 3;
    int j = lane & 7;
    int hb = lane & ~7;

    float qf[16];
    {
        U8 q0, q1;
        const ushort* qp = qb + (size_t)n * DD + h * HDD;
        q0.v = *(const int4*)qp;
        q1.v = *(const int4*)(qp + 8);
#pragma unroll
        for (int t = 0; t < 8; t++) qf[t] = bf2f(q0.u[t]);
#pragma unroll
        for (int t = 0; t < 8; t++) qf[8 + t] = bf2f(q1.u[t]);
    }

    float m = -INFINITY;
    float denom = 0.f;
    float acc0 = 0.f, acc1 = 0.f;

    for (int idx = 0; idx < cnt; idx += 8) {
        int my = idx + j;
        bool valid = my < cnt;
        int2 re = valid ? bucket[my] : make_int2(0, 0);
        int r = re.x;
        float logit = -INFINITY;
        if (valid) {
            const ushort* kp = kk + (size_t)r * DD + h * HDD;
            U8 a0, a1;
            a0.v = *(const int4*)kp;
            a1.v = *(const int4*)(kp + 8);
            float d = 0.f;
#pragma unroll
            for (int t = 0; t < 8; t++) d += qf[t] * bf2f(a0.u[t]);
#pragma unroll
            for (int t = 0; t < 8; t++) d += qf[8 + t] * bf2f(a1.u[t]);
            logit = d + ebias[(size_t)re.y * HH + h];
        }
        float cm = logit;
        cm = fmaxf(cm, __shfl_xor(cm, 1));
        cm = fmaxf(cm, __shfl_xor(cm, 2));
        cm = fmaxf(cm, __shfl_xor(cm, 4));
        float mnew = fmaxf(m, cm);
        float sc = __expf(m - mnew);
        float p = __expf(logit - mnew);
        m = mnew;
        float ps = p;
        ps += __shfl_xor(ps, 1);
        ps += __shfl_xor(ps, 2);
        ps += __shfl_xor(ps, 4);
        denom = denom * sc + ps;
        acc0 *= sc;
        acc1 *= sc;
#pragma unroll
        for (int j2 = 0; j2 < 8; j2++) {
            float pj = __shfl(p, hb + j2);
            int rj = __shfl(r, hb + j2);
            uint vp = *(const uint*)(vv + (size_t)rj * DD + 2 * lane);
            acc0 += pj * bf2f((ushort)(vp & 0xffffu));
            acc1 += pj * bf2f((ushort)(vp >> 16));
        }
    }
    float inv = 1.0f / (denom + 1e-16f);
    uint pack = (uint)f2bf(acc0 * inv) | ((uint)f2bf(acc1 * inv) << 16);
    *(uint*)&aggb[(size_t)n * DD + 2 * lane] = pack;
}

// ---------------- launcher ----------------
extern "C" void kernel_launch(void* const* d_in, const int* in_sizes, int n_in,
                              void* d_out, int out_size, void* d_ws, size_t ws_size,
                              hipStream_t stream) {
    const float* x     = (const float*)d_in[0];
    const int*   eidx  = (const int*)d_in[1];
    const float* ebias = (const float*)d_in[2];
    const float* Wq    = (const float*)d_in[3];
    const float* bq    = (const float*)d_in[4];
    const float* Wk    = (const float*)d_in[5];
    const float* bk    = (const float*)d_in[6];
    const float* Wv    = (const float*)d_in[7];
    const float* bv    = (const float*)d_in[8];
    const float* Wo    = (const float*)d_in[9];
    const float* bo    = (const float*)d_in[10];
    float* out = (float*)d_out;

    const int* row = eidx;        // edge_index[0]
    const int* col = eidx + EE;   // edge_index[1]

    // workspace layout (16B-aligned chunks)
    char* p = (char*)d_ws;
    ushort* qb    = (ushort*)p;  p += (size_t)NN * DD * 2;   // 12.8 MB
    ushort* kk    = (ushort*)p;  p += (size_t)NN * DD * 2;   // 12.8 MB
    ushort* vvp   = (ushort*)p;  p += (size_t)NN * DD * 2;   // 12.8 MB
    ushort* aggb  = (ushort*)p;  p += (size_t)NN * DD * 2;   // 12.8 MB
    ushort* Wt    = (ushort*)p;  p += (size_t)4 * 16384 * 2;
    float*  bpk   = (float*)p;   p += 4 * 128 * 4;
    int2*   reB   = (int2*)p;    p += (size_t)NN * CAP * 8;  // 25.6 MB
    int* cursor   = (int*)p;     p += (size_t)NN * CSTR * 4; // 3.2 MB padded

    hipMemsetAsync(cursor, 0, (size_t)NN * CSTR * sizeof(int), stream);

    hipLaunchKernelGGL(k_prep, dim3(256), dim3(256), 0, stream,
                       Wq, Wk, Wv, Wo, bq, bk, bv, bo, Wt, bpk);

    hipLaunchKernelGGL(k_pre, dim3(PREB), dim3(256), 0, stream,
                       x, Wt, bpk, qb, kk, vvp, col, row, cursor, reB);

    hipLaunchKernelGGL(k_attn, dim3(NN / 4), dim3(256), 0, stream,
                       qb, kk, vvp, ebias, reB, cursor, aggb);

    hipLaunchKernelGGL(k_gemm_out, dim3(QB), dim3(256), 0, stream,
                       aggb, Wt + 3 * 16384, bpk + 3 * 128, out);
}

// Round 14
// 178.135 us; speedup vs baseline: 1.4003x; 1.0142x over previous
//
#include <hip/hip_runtime.h>
#include <math.h>

#define NN 50000
#define EE 800000
#define DD 128
#define HH 8
#define HDD 16
#define CAP 64      // bucket capacity; P(degree>=64 | Poisson(16)) ~ 1e-18/node
#define NXCD 8
#define NPG 6250    // nodes per XCD group (NN/8)
#define SL 2048     // edges per fill slice
#define NSL 391     // ceil(EE/SL) slices per group
#define NSTRIP 3125 // NN/16 strips of 16 rows
#define QB 782      // ceil(NSTRIP/4) qkv blocks (4 waves = 4 strips each)
#define FILLB 3128  // 8 groups x 391 slices
#define LTS 130     // padded ushort stride for transpose buffer

typedef __attribute__((ext_vector_type(8))) short short8;
typedef __attribute__((ext_vector_type(4))) float f32x4;

union U8 { ushort u[8]; int4 v; short8 s; };

__device__ __forceinline__ ushort f2bf(float f) {
    uint u = __float_as_uint(f);
    uint r = (u + 0x7fffu + ((u >> 16) & 1u)) >> 16;
    return (ushort)r;
}
__device__ __forceinline__ float bf2f(ushort u) {
    return __uint_as_float(((uint)u) << 16);
}

// ---------------- prep: pack W^T bf16 (+bias, q scaled) ----------------
__global__ void k_prep(const float* __restrict__ Wq, const float* __restrict__ Wk,
                       const float* __restrict__ Wv, const float* __restrict__ Wo,
                       const float* __restrict__ bq, const float* __restrict__ bk,
                       const float* __restrict__ bv, const float* __restrict__ bo,
                       ushort* __restrict__ Wt, float* __restrict__ bpack) {
    int tid = blockIdx.x * 256 + threadIdx.x;  // 4*128*128
    int w = tid >> 14, rem = tid & 16383, c = rem >> 7, i = rem & 127;
    const float* W = (w == 0) ? Wq : (w == 1) ? Wk : (w == 2) ? Wv : Wo;
    float s = (w == 0) ? 0.25f : 1.0f;
    Wt[(size_t)w * 16384 + c * 128 + i] = f2bf(W[i * 128 + c] * s);
    if (i == 0) {
        const float* B = (w == 0) ? bq : (w == 1) ? bk : (w == 2) ? bv : bo;
        bpack[w * 128 + c] = B[c] * s;
    }
}

// ------- fused pre-pass: QKV strip-GEMM (b<QB) + XCD-partitioned fill -------
// Fill: group g = b&7 owns nodes [g*NPG,(g+1)*NPG); scans its own 2048-edge
// slice, keeps only in-range edges -> all cursor/reB lines single-XCD, bucket
// range (3.2 MB) fits that XCD's 4MB L2 -> write merge + local atomics.
__global__ __launch_bounds__(256) void k_pre(
    const float* __restrict__ x, const ushort* __restrict__ Wt,
    const float* __restrict__ bpk,
    ushort* __restrict__ qb, ushort* __restrict__ kk, ushort* __restrict__ vv,
    const int* __restrict__ col, const int* __restrict__ row,
    int* __restrict__ cursor, int2* __restrict__ reB) {
    __shared__ ushort T[4][16 * LTS];  // 16.6 KB
    int tid = threadIdx.x;
    int b = blockIdx.x;

    if (b >= QB) {
        // ---- XCD-partitioned bucket fill ----
        int fi = b - QB;                      // 0..3127
        int g = b & 7;                        // XCD residue class (dispatch b%8)
        int j = fi >> 3;                      // slice 0..390 within group
        int lo = g * NPG, hi = lo + NPG;
        int base = j * SL + tid * 8;
        if (base < EE) {
            int4 c0 = *(const int4*)&col[base];
            int4 c1 = *(const int4*)&col[base + 4];
            int cs[8] = {c0.x, c0.y, c0.z, c0.w, c1.x, c1.y, c1.z, c1.w};
            int lim = EE - base;  // slice tail clamp (only last slice: lim<8)
#pragma unroll
            for (int t = 0; t < 8; t++) {
                if (t < lim) {
                    int c = cs[t];
                    if (c >= lo && c < hi) {
                        int e = base + t;
                        int p = atomicAdd(&cursor[c], 1);
                        if (p < CAP) reB[(size_t)c * CAP + p] = make_int2(row[e], e);
                    }
                }
            }
        }
        return;
    }

    // ---- QKV strip (16 rows x 128 cols), one strip per wave ----
    int wave = tid >> 6, lane = tid & 63;
    int strip = b * 4 + wave;
    if (strip >= NSTRIP) return;
    int r0 = strip * 16;
    int lr = lane & 15, lg = lane >> 4;
    ushort* Tw = T[wave];

    // A-fragments: row r0+lr, k-slices ks*32 + lg*8 (fp32 -> bf16)
    short8 afr[4];
    const float* xp = x + (size_t)(r0 + lr) * 128;
#pragma unroll
    for (int ks = 0; ks < 4; ks++) {
        const float* ap = xp + ks * 32 + lg * 8;
        float4 f0 = *(const float4*)ap;
        float4 f1 = *(const float4*)(ap + 4);
        U8 r;
        r.u[0] = f2bf(f0.x); r.u[1] = f2bf(f0.y); r.u[2] = f2bf(f0.z); r.u[3] = f2bf(f0.w);
        r.u[4] = f2bf(f1.x); r.u[5] = f2bf(f1.y); r.u[6] = f2bf(f1.z); r.u[7] = f2bf(f1.w);
        afr[ks] = r.s;
    }

    for (int w = 0; w < 3; w++) {
        f32x4 acc[8];
#pragma unroll
        for (int n = 0; n < 8; n++) acc[n] = (f32x4){0.f, 0.f, 0.f, 0.f};
        const ushort* Wb = Wt + (size_t)w * 16384;
#pragma unroll
        for (int ks = 0; ks < 4; ks++) {
            short8 bfr[8];
#pragma unroll
            for (int n = 0; n < 8; n++)
                bfr[n] = *(const short8*)&Wb[(n * 16 + lr) * 128 + ks * 32 + lg * 8];
#pragma unroll
            for (int n = 0; n < 8; n++)
                acc[n] = __builtin_amdgcn_mfma_f32_16x16x32_bf16(afr[ks], bfr[n], acc[n], 0, 0, 0);
        }

        // epilogue: transpose via per-wave LDS, then coalesced 1KB stores
#pragma unroll
        for (int n = 0; n < 8; n++) {
            float bv_ = bpk[w * 128 + n * 16 + lr];
#pragma unroll
            for (int rg = 0; rg < 4; rg++)
                Tw[(lg * 4 + rg) * LTS + n * 16 + lr] = f2bf(acc[n][rg] + bv_);
        }
        ushort* dst = (w == 0) ? qb : (w == 1) ? kk : vv;
#pragma unroll
        for (int i = 0; i < 4; i++) {
            int4 vd = *(const int4*)&Tw[(i * 4 + lg) * LTS + lr * 8];
            *(int4*)&dst[(size_t)(r0 + i * 4 + lg) * 128 + lr * 8] = vd;
        }
    }
}

// ---------------- output projection: LDS-free strip GEMM -------------------
__global__ __launch_bounds__(256) void k_gemm_out(
    const ushort* __restrict__ A, const ushort* __restrict__ Bt,
    const float* __restrict__ bias, float* __restrict__ Cf) {
    int tid = threadIdx.x;
    int wave = tid >> 6, lane = tid & 63;
    int strip = blockIdx.x * 4 + wave;
    if (strip >= NSTRIP) return;
    int r0 = strip * 16;
    int lr = lane & 15, lg = lane >> 4;

    short8 afr[4];
#pragma unroll
    for (int ks = 0; ks < 4; ks++)
        afr[ks] = *(const short8*)&A[(size_t)(r0 + lr) * 128 + ks * 32 + lg * 8];

    f32x4 acc[8];
#pragma unroll
    for (int n = 0; n < 8; n++) acc[n] = (f32x4){0.f, 0.f, 0.f, 0.f};
#pragma unroll
    for (int ks = 0; ks < 4; ks++) {
        short8 bfr[8];
#pragma unroll
        for (int n = 0; n < 8; n++)
            bfr[n] = *(const short8*)&Bt[(n * 16 + lr) * 128 + ks * 32 + lg * 8];
#pragma unroll
        for (int n = 0; n < 8; n++)
            acc[n] = __builtin_amdgcn_mfma_f32_16x16x32_bf16(afr[ks], bfr[n], acc[n], 0, 0, 0);
    }
#pragma unroll
    for (int n = 0; n < 8; n++) {
        int gcol = n * 16 + lr;
        float bv_ = bias[gcol];
#pragma unroll
        for (int rg = 0; rg < 4; rg++) {
            int grow = r0 + lg * 4 + rg;
            Cf[(size_t)grow * 128 + gcol] = acc[n][rg] + bv_;
        }
    }
}

// ---------------- per-node attention, online softmax in registers ----------
__global__ __launch_bounds__(256) void k_attn(
    const ushort* __restrict__ qb, const ushort* __restrict__ kk,
    const ushort* __restrict__ vv, const float* __restrict__ ebias,
    const int2* __restrict__ reB, const int* __restrict__ deg,
    ushort* __restrict__ aggb) {
    int wave = threadIdx.x >> 6;
    int lane = threadIdx.x & 63;
    int n = blockIdx.x * 4 + wave;
    if (n >= NN) return;
    int cnt = min(deg[n], CAP);
    const int2* bucket = reB + (size_t)n * CAP;
    int h = lane >> 3;
    int j = lane & 7;
    int hb = lane & ~7;

    float qf[16];
    {
        U8 q0, q1;
        const ushort* qp = qb + (size_t)n * DD + h * HDD;
        q0.v = *(const int4*)qp;
        q1.v = *(const int4*)(qp + 8);
#pragma unroll
        for (int t = 0; t < 8; t++) qf[t] = bf2f(q0.u[t]);
#pragma unroll
        for (int t = 0; t < 8; t++) qf[8 + t] = bf2f(q1.u[t]);
    }

    float m = -INFINITY;
    float denom = 0.f;
    float acc0 = 0.f, acc1 = 0.f;

    for (int idx = 0; idx < cnt; idx += 8) {
        int my = idx + j;
        bool valid = my < cnt;
        int2 re = valid ? bucket[my] : make_int2(0, 0);
        int r = re.x;
        float logit = -INFINITY;
        if (valid) {
            const ushort* kp = kk + (size_t)r * DD + h * HDD;
            U8 a0, a1;
            a0.v = *(const int4*)kp;
            a1.v = *(const int4*)(kp + 8);
            float d = 0.f;
#pragma unroll
            for (int t = 0; t < 8; t++) d += qf[t] * bf2f(a0.u[t]);
#pragma unroll
            for (int t = 0; t < 8; t++) d += qf[8 + t] * bf2f(a1.u[t]);
            logit = d + ebias[(size_t)re.y * HH + h];
        }
        float cm = logit;
        cm = fmaxf(cm, __shfl_xor(cm, 1));
        cm = fmaxf(cm, __shfl_xor(cm, 2));
        cm = fmaxf(cm, __shfl_xor(cm, 4));
        float mnew = fmaxf(m, cm);
        float sc = __expf(m - mnew);
        float p = __expf(logit - mnew);
        m = mnew;
        float ps = p;
        ps += __shfl_xor(ps, 1);
        ps += __shfl_xor(ps, 2);
        ps += __shfl_xor(ps, 4);
        denom = denom * sc + ps;
        acc0 *= sc;
        acc1 *= sc;
#pragma unroll
        for (int j2 = 0; j2 < 8; j2++) {
            float pj = __shfl(p, hb + j2);
            int rj = __shfl(r, hb + j2);
            uint vp = *(const uint*)(vv + (size_t)rj * DD + 2 * lane);
            acc0 += pj * bf2f((ushort)(vp & 0xffffu));
            acc1 += pj * bf2f((ushort)(vp >> 16));
        }
    }
    float inv = 1.0f / (denom + 1e-16f);
    uint pack = (uint)f2bf(acc0 * inv) | ((uint)f2bf(acc1 * inv) << 16);
    *(uint*)&aggb[(size_t)n * DD + 2 * lane] = pack;
}

// ---------------- launcher ----------------
extern "C" void kernel_launch(void* const* d_in, const int* in_sizes, int n_in,
                              void* d_out, int out_size, void* d_ws, size_t ws_size,
                              hipStream_t stream) {
    const float* x     = (const float*)d_in[0];
    const int*   eidx  = (const int*)d_in[1];
    const float* ebias = (const float*)d_in[2];
    const float* Wq    = (const float*)d_in[3];
    const float* bq    = (const float*)d_in[4];
    const float* Wk    = (const float*)d_in[5];
    const float* bk    = (const float*)d_in[6];
    const float* Wv    = (const float*)d_in[7];
    const float* bv    = (const float*)d_in[8];
    const float* Wo    = (const float*)d_in[9];
    const float* bo    = (const float*)d_in[10];
    float* out = (float*)d_out;

    const int* row = eidx;        // edge_index[0]
    const int* col = eidx + EE;   // edge_index[1]

    // workspace layout (16B-aligned chunks)
    char* p = (char*)d_ws;
    ushort* qb    = (ushort*)p;  p += (size_t)NN * DD * 2;   // 12.8 MB
    ushort* kk    = (ushort*)p;  p += (size_t)NN * DD * 2;   // 12.8 MB
    ushort* vvp   = (ushort*)p;  p += (size_t)NN * DD * 2;   // 12.8 MB
    ushort* aggb  = (ushort*)p;  p += (size_t)NN * DD * 2;   // 12.8 MB
    ushort* Wt    = (ushort*)p;  p += (size_t)4 * 16384 * 2;
    float*  bpk   = (float*)p;   p += 4 * 128 * 4;
    int2*   reB   = (int2*)p;    p += (size_t)NN * CAP * 8;  // 25.6 MB
    int* cursor   = (int*)p;     p += (size_t)NN * 4;

    hipMemsetAsync(cursor, 0, (size_t)NN * sizeof(int), stream);

    hipLaunchKernelGGL(k_prep, dim3(256), dim3(256), 0, stream,
                       Wq, Wk, Wv, Wo, bq, bk, bv, bo, Wt, bpk);

    hipLaunchKernelGGL(k_pre, dim3(QB + FILLB), dim3(256), 0, stream,
                       x, Wt, bpk, qb, kk, vvp, col, row, cursor, reB);

    hipLaunchKernelGGL(k_attn, dim3(NN / 4), dim3(256), 0, stream,
                       qb, kk, vvp, ebias, reB, cursor, aggb);

    hipLaunchKernelGGL(k_gemm_out, dim3((NSTRIP + 3) / 4), dim3(256), 0, stream,
                       aggb, Wt + 3 * 16384, bpk + 3 * 128, out);
}